// Round 9
// baseline (385.520 us; speedup 1.0000x reference)
//
#include <hip/hip_runtime.h>
#include <math.h>

#define BB 1024
#define LSx 128
#define LLx 2048
#define TOPKx 48

// ---------------------------------------------------------------------------
// Kernel 1: heterogeneous grid — 9216 blocks of 256 threads.
//   bid % 9 == 0  -> short-MHA block (1024 of them), b = bid/9
//   else          -> LSH score chunk (8192), idx = bid - bid/9 - 1,
//                    b = idx>>3, chunk = idx&7   (verbatim R6 score body)
// Interleaving 1 short : 8 score keeps both kinds co-resident on every CU:
// score is HBM-bound (3.3 TB/s, VALU 49%), short-MHA is VALU-bound and does
// NOT depend on gsc -> short-MHA hides under score's memory stalls (m114:
// separate pipes co-schedule). LDS is a union (20.7 KB = score footprint,
// score occupancy unchanged). Short path = verbatim R8 chunked-V structure.
// ---------------------------------------------------------------------------
struct SmemScore {
  float4 xsh[256][5];          // padded rows: 20-word stride, conflict-floor
  float Xitem[48];
  int icode[16];
};
struct SmemShort {
  float vhsT[48][65];          // transposed, 64-col chunk (+pad)
  float scs[8][LSx + 4];
  float Xitem[48];
  float qh[48];
  float osm[48];
  unsigned char validf[LSx];
};

__global__ __launch_bounds__(256, 2) void k_score_short(
    const int* __restrict__ lg, const int* __restrict__ lsh, const int* __restrict__ lc,
    const int* __restrict__ sg, const int* __restrict__ ss, const int* __restrict__ scd,
    const int* __restrict__ ig, const int* __restrict__ ish, const int* __restrict__ ici,
    const float* __restrict__ emb, const float* __restrict__ Hm,
    const float* __restrict__ sWq, const float* __restrict__ sbq,
    const float* __restrict__ sWk, const float* __restrict__ sbk,
    const float* __restrict__ sWv, const float* __restrict__ sbv,
    const float* __restrict__ sWo, const float* __restrict__ sbo,
    signed char* __restrict__ gsc, float* __restrict__ sint)
{
  __shared__ union { SmemScore a; SmemShort m; } sm;
  const int bid = blockIdx.x, tid = threadIdx.x;

  if (bid % 9 != 0) {
    // ================= score path (verbatim R6 80us kernel) =================
    const int idx = bid - bid / 9 - 1;
    const int b = idx >> 3;
    const int chunk = idx & 7;

    const int l = chunk * 256 + tid;
    const size_t off = (size_t)b * LLx + l;
    const int gid = lg[off];

    if (tid < 48) {
      const int seg = tid >> 4, e = tid & 15;
      const int id = (seg == 0) ? ig[b] : (seg == 1) ? ish[b] : ici[b];
      sm.a.Xitem[tid] = emb[(size_t)id * 16 + e];
    }
    __syncthreads();
    if (tid < 16) {
      float dd = 0.f;
      for (int e = 0; e < 48; ++e) dd += sm.a.Xitem[e] * Hm[e * 16 + tid];
      sm.a.icode[tid] = (dd > 0.f) ? 1 : (dd < 0.f ? -1 : 0);
    }

    const int srow = tid >> 2;
    const int q = tid & 3;
    const size_t bbase = (size_t)b * LLx + (size_t)chunk * 256;

    float d[16];
    #pragma unroll
    for (int m = 0; m < 16; ++m) d[m] = 0.f;

    #pragma unroll
    for (int seg = 0; seg < 3; ++seg) {
      const int* idarr = (seg == 0) ? lg : (seg == 1) ? lsh : lc;
      #pragma unroll
      for (int jj = 0; jj < 4; ++jj) {
        const int pos = jj * 64 + srow;
        const int id = idarr[bbase + pos];
        sm.a.xsh[pos][q] = *(const float4*)(emb + (size_t)id * 16 + q * 4);
      }
      __syncthreads();
      if (gid != 0) {
        float x[16];
        #pragma unroll
        for (int qq = 0; qq < 4; ++qq) {
          const float4 r = sm.a.xsh[tid][qq];
          x[qq * 4 + 0] = r.x; x[qq * 4 + 1] = r.y;
          x[qq * 4 + 2] = r.z; x[qq * 4 + 3] = r.w;
        }
        const float* hb = Hm + seg * 256;
        #pragma unroll
        for (int i = 0; i < 16; ++i) {
          const float xi = x[i];
          #pragma unroll
          for (int mc = 0; mc < 4; ++mc) {
            const float4 h4 = *(const float4*)(hb + i * 16 + mc * 4);
            d[mc * 4 + 0] += xi * h4.x;
            d[mc * 4 + 1] += xi * h4.y;
            d[mc * 4 + 2] += xi * h4.z;
            d[mc * 4 + 3] += xi * h4.w;
          }
        }
      }
      if (seg < 2) __syncthreads();
    }

    int sc = -1;
    if (gid != 0) {
      sc = 0;
      #pragma unroll
      for (int m = 0; m < 16; ++m) {
        const int cs = (d[m] > 0.f) ? 1 : (d[m] < 0.f ? -1 : 0);
        sc += (cs == sm.a.icode[m]) ? 1 : 0;
      }
    }
    gsc[off] = (signed char)sc;
    return;
  }

  // ================= short-MHA path (verbatim R8 chunked-V) =================
  const int b = bid / 9;
  const int t = tid;    // tid<128 active; 128..255 barrier-only

  if (tid < 48) {
    const int seg = tid >> 4, e = tid & 15;
    const int id = (seg == 0) ? ig[b] : (seg == 1) ? ish[b] : ici[b];
    sm.m.Xitem[tid] = emb[(size_t)id * 16 + e];
  }
  __syncthreads();
  if (tid < 48) {
    float a = sbq[tid];
    for (int e = 0; e < 48; ++e) a += sm.m.Xitem[e] * sWq[e * 48 + tid];
    sm.m.qh[tid] = a;
  }

  int gid = 0, sid = 0, cid = 0;
  if (tid < 128) {
    const size_t off = (size_t)b * LSx + t;
    gid = sg[off]; sid = ss[off]; cid = scd[off];
  }
  const int nval = __syncthreads_count((tid < 128) && (gid != 0));  // qh visible

  float vh[48];                       // threads 64..127 hold this into P7b
  if (tid < 128) {
    sm.m.validf[t] = (unsigned char)(t < nval);
    float kh[48];
    #pragma unroll
    for (int j = 0; j < 48; ++j) { kh[j] = sbk[j]; vh[j] = sbv[j]; }
    const int ids3[3] = {gid, sid, cid};
    #pragma unroll
    for (int seg = 0; seg < 3; ++seg) {
      const float* row = emb + (size_t)ids3[seg] * 16;
      #pragma unroll
      for (int i4 = 0; i4 < 4; ++i4) {
        const float4 xv = ((const float4*)row)[i4];
        const float xs[4] = {xv.x, xv.y, xv.z, xv.w};
        #pragma unroll
        for (int c = 0; c < 4; ++c) {
          const int e = seg * 16 + i4 * 4 + c;
          const float* wkr = sWk + e * 48;
          const float* wvr = sWv + e * 48;
          const float xe = xs[c];
          #pragma unroll
          for (int j = 0; j < 48; ++j) {
            kh[j] += xe * wkr[j];
            vh[j] += xe * wvr[j];
          }
        }
      }
    }
    #pragma unroll
    for (int h = 0; h < 8; ++h) {
      float s = 0.f;
      #pragma unroll
      for (int d2 = 0; d2 < 6; ++d2) s += sm.m.qh[h * 6 + d2] * kh[h * 6 + d2];
      sm.m.scs[h][t] = s * 0.40824829046386301637f;   // 1/sqrt(6)
    }
    if (t < 64) {                      // chunk 0 stores now; t>=64 holds vh
      #pragma unroll
      for (int j = 0; j < 48; ++j) sm.m.vhsT[j][t] = vh[j];
    }
  }
  __syncthreads();

  if (tid < 128) {
    const int h = t >> 4, l16 = t & 15;
    float amax = -INFINITY;
    for (int k = l16; k < LSx; k += 16) if (sm.m.validf[k]) amax = fmaxf(amax, sm.m.scs[h][k]);
    #pragma unroll
    for (int m = 1; m < 16; m <<= 1) amax = fmaxf(amax, __shfl_xor(amax, m, 16));
    if (nval == 0) {
      for (int k = l16; k < LSx; k += 16) sm.m.scs[h][k] = 1.0f / (float)LSx;
    } else {
      float ssum = 0.f;
      for (int k = l16; k < LSx; k += 16) {
        const float ev = sm.m.validf[k] ? expf(sm.m.scs[h][k] - amax) : 0.f;
        sm.m.scs[h][k] = ev;
        ssum += ev;
      }
      #pragma unroll
      for (int m = 1; m < 16; m <<= 1) ssum += __shfl_xor(ssum, m, 16);
      const float inv = 1.0f / ssum;
      for (int k = l16; k < LSx; k += 16) sm.m.scs[h][k] *= inv;
    }
  }
  __syncthreads();

  // PV pass 0 (k=0..63)
  float acc = 0.f;
  int hh = 0;
  if (tid < 48) {
    hh = tid / 6;
    for (int k = 0; k < 64; ++k) acc += sm.m.scs[hh][k] * sm.m.vhsT[tid][k];
  }
  __syncthreads();
  // chunk-1 V store
  if (tid >= 64 && tid < 128) {
    #pragma unroll
    for (int j = 0; j < 48; ++j) sm.m.vhsT[j][t - 64] = vh[j];
  }
  __syncthreads();
  // PV pass 1 (k=64..127; same accumulator, same order)
  if (tid < 48) {
    for (int k = 64; k < LSx; ++k) acc += sm.m.scs[hh][k] * sm.m.vhsT[tid][k - 64];
    sm.m.osm[tid] = acc;
  }
  __syncthreads();
  if (tid < 48) {
    float r = sbo[tid];
    for (int j = 0; j < 48; ++j) r += sm.m.osm[j] * sWo[j * 48 + tid];
    sint[b * 48 + tid] = r;
  }
}

// ---------------------------------------------------------------------------
// Kernel 2: topk + long-MHA + MLP (verbatim R8 phases minus the short half;
// sint read from global). One 256-thread block per batch element.
// ---------------------------------------------------------------------------
__device__ __forceinline__ float block_sum256(float v, float* red) {
  #pragma unroll
  for (int m = 32; m >= 1; m >>= 1) v += __shfl_xor(v, m, 64);
  const int lane = threadIdx.x & 63, wave = threadIdx.x >> 6;
  if (lane == 0) red[wave] = v;
  __syncthreads();
  const float t = red[0] + red[1] + red[2] + red[3];
  __syncthreads();
  return t;
}

__global__ __launch_bounds__(256, 2) void k_long_mlp(
    const int* __restrict__ lg, const int* __restrict__ ls, const int* __restrict__ lcd,
    const int* __restrict__ ig, const int* __restrict__ ish, const int* __restrict__ ici,
    const int* __restrict__ uid, const int* __restrict__ u1, const int* __restrict__ u2,
    const int* __restrict__ u3, const int* __restrict__ u4,
    const float* __restrict__ emb,
    const float* __restrict__ lWq, const float* __restrict__ lbq,
    const float* __restrict__ lWk, const float* __restrict__ lbk,
    const float* __restrict__ lWv, const float* __restrict__ lbv,
    const float* __restrict__ lWo, const float* __restrict__ lbo,
    const signed char* __restrict__ gsc, const float* __restrict__ sint,
    const float* __restrict__ W1, const float* __restrict__ b1,
    const float* __restrict__ g1, const float* __restrict__ be1,
    const float* __restrict__ W2, const float* __restrict__ b2,
    const float* __restrict__ g2, const float* __restrict__ be2,
    const float* __restrict__ W3, const float* __restrict__ b3,
    float* __restrict__ out)
{
  __shared__ float Xitem[48];
  __shared__ float qh_l[48];
  __shared__ float vhs_lT[48][TOPKx + 1];
  __shared__ float scs_l[8][TOPKx + 4];
  __shared__ float osm_l[48];
  __shared__ unsigned char validf_l[TOPKx];
  __shared__ int hist[18], wsum[4], selsh[TOPKx];
  __shared__ int cnt_above;
  __shared__ __align__(16) float x[224];
  __shared__ __align__(16) float h1[200];
  __shared__ float h2[80];
  __shared__ float red[4];

  const int b = blockIdx.x, tid = threadIdx.x;

  // each thread owns 8 contiguous scores, in registers (verbatim k_topk)
  const int2 myv = ((const int2*)(gsc + (size_t)b * LLx))[tid];
  signed char loc[8];
  *(int2*)loc = myv;

  // ---- P0 ----
  if (tid < 48) {
    const int seg = tid >> 4, e = tid & 15;
    const int id = (seg == 0) ? ig[b] : (seg == 1) ? ish[b] : ici[b];
    Xitem[tid] = emb[(size_t)id * 16 + e];
  } else if (tid >= 112 && tid < 160) {
    x[128 + (tid - 112)] = sint[b * 48 + (tid - 112)];
  } else if (tid >= 160 && tid < 240) {
    const int u = tid - 160;
    const int f = u >> 4;
    const int id = (f == 0) ? uid[b] : (f == 1) ? u1[b] : (f == 2) ? u2[b]
                 : (f == 3) ? u3[b] : u4[b];
    x[48 + u] = emb[(size_t)id * 16 + (u & 15)];
  }
  if (tid < 18) hist[tid] = 0;
  if (tid == 0) cnt_above = 0;
  __syncthreads();

  // ---- P1: hist atomics + long q proj + x[0:48] copy ----
  #pragma unroll
  for (int j = 0; j < 8; ++j) atomicAdd(&hist[(int)loc[j] + 1], 1);
  if (tid < 48) {
    float a = lbq[tid];
    for (int e = 0; e < 48; ++e) a += Xitem[e] * lWq[e * 48 + tid];
    qh_l[tid] = a;
  } else if (tid >= 64 && tid < 112) {
    x[tid - 64] = Xitem[tid - 64];
  }
  __syncthreads();

  // ---- P2: threshold + tie-rank scan (verbatim) ----
  int above = 0, tval = -1, need = 0;
  for (int s = 16; s >= -1; --s) {
    const int c = hist[s + 1];
    if (above + c >= TOPKx) { tval = s; need = TOPKx - above; break; }
    above += c;
  }
  const int base_l = tid * (LLx / 256);
  int cnt = 0;
  #pragma unroll
  for (int j = 0; j < 8; ++j) cnt += ((int)loc[j] == tval) ? 1 : 0;
  int v = cnt;
  const int lane = tid & 63, wave = tid >> 6;
  #pragma unroll
  for (int o = 1; o < 64; o <<= 1) {
    const int u = __shfl_up(v, o, 64);
    if (lane >= o) v += u;
  }
  if (lane == 63) wsum[wave] = v;
  __syncthreads();
  int rank = v - cnt;
  for (int w = 0; w < wave; ++w) rank += wsum[w];

  #pragma unroll
  for (int j = 0; j < 8; ++j) {
    const int l = base_l + j;
    const int s = (int)loc[j];
    if (s > tval) {
      const int slot = atomicAdd(&cnt_above, 1);
      selsh[slot] = l;
    } else if (s == tval) {
      if (rank < need) selsh[above + rank] = l;
      ++rank;
    }
  }
  __syncthreads();   // selsh ready

  // ---- P4: long ids + valid count ----
  int gid = 0, sid = 0, cid = 0;
  if (tid < TOPKx) {
    const int pos = selsh[tid];
    const size_t off = (size_t)b * LLx + pos;
    gid = lg[off]; sid = ls[off]; cid = lcd[off];
  }
  const int nval = __syncthreads_count((tid < TOPKx) && (gid != 0));

  // ---- P5: long K/V proj (verbatim chain, transposed V store) ----
  if (tid < TOPKx) {
    validf_l[tid] = (unsigned char)(gid != 0);
    float kh[48], vh[48];
    #pragma unroll
    for (int j = 0; j < 48; ++j) { kh[j] = lbk[j]; vh[j] = lbv[j]; }
    const int ids3[3] = {gid, sid, cid};
    #pragma unroll
    for (int seg = 0; seg < 3; ++seg) {
      const float* row = emb + (size_t)ids3[seg] * 16;
      #pragma unroll
      for (int i4 = 0; i4 < 4; ++i4) {
        const float4 xv = ((const float4*)row)[i4];
        const float xs[4] = {xv.x, xv.y, xv.z, xv.w};
        #pragma unroll
        for (int c = 0; c < 4; ++c) {
          const int e = seg * 16 + i4 * 4 + c;
          const float* wkr = lWk + e * 48;
          const float* wvr = lWv + e * 48;
          const float xe = xs[c];
          #pragma unroll
          for (int j = 0; j < 48; ++j) {
            kh[j] += xe * wkr[j];
            vh[j] += xe * wvr[j];
          }
        }
      }
    }
    #pragma unroll
    for (int h = 0; h < 8; ++h) {
      float s = 0.f;
      #pragma unroll
      for (int d2 = 0; d2 < 6; ++d2) s += qh_l[h * 6 + d2] * kh[h * 6 + d2];
      scs_l[h][tid] = s * 0.40824829046386301637f;
    }
    #pragma unroll
    for (int j = 0; j < 48; ++j) vhs_lT[j][tid] = vh[j];
  }
  __syncthreads();

  // ---- P6: softmax (verbatim, threads 0..127) ----
  if (tid < 128) {
    const int h = tid >> 4, l16 = tid & 15;
    float amax = -INFINITY;
    for (int k = l16; k < TOPKx; k += 16) if (validf_l[k]) amax = fmaxf(amax, scs_l[h][k]);
    #pragma unroll
    for (int m = 1; m < 16; m <<= 1) amax = fmaxf(amax, __shfl_xor(amax, m, 16));
    if (nval == 0) {
      for (int k = l16; k < TOPKx; k += 16) scs_l[h][k] = 1.0f / (float)TOPKx;
    } else {
      float ssum = 0.f;
      for (int k = l16; k < TOPKx; k += 16) {
        const float ev = validf_l[k] ? expf(scs_l[h][k] - amax) : 0.f;
        scs_l[h][k] = ev;
        ssum += ev;
      }
      #pragma unroll
      for (int m = 1; m < 16; m <<= 1) ssum += __shfl_xor(ssum, m, 16);
      const float inv = 1.0f / ssum;
      for (int k = l16; k < TOPKx; k += 16) scs_l[h][k] *= inv;
    }
  }
  __syncthreads();

  // ---- P7: PV ----
  if (tid < 48) {
    const int h = tid / 6;
    float a = 0.f;
    for (int k = 0; k < TOPKx; ++k) a += scs_l[h][k] * vhs_lT[tid][k];
    osm_l[tid] = a;
  }
  __syncthreads();

  // ---- P8: out proj -> x[176..224) ----
  if (tid < 48) {
    float r = lbo[tid];
    for (int j = 0; j < 48; ++j) r += osm_l[j] * lWo[j * 48 + tid];
    x[176 + tid] = r;
  }
  __syncthreads();

  // ---- P9: MLP head (verbatim) ----
  float v1 = 0.f;
  if (tid < 200) {
    v1 = b1[tid];
    for (int i4 = 0; i4 < 56; ++i4) {
      const float4 xv = *(const float4*)(x + i4 * 4);
      const float* w = W1 + i4 * 4 * 200 + tid;
      v1 += xv.x * w[0];
      v1 += xv.y * w[200];
      v1 += xv.z * w[400];
      v1 += xv.w * w[600];
    }
  }
  const float mean1 = block_sum256((tid < 200) ? v1 : 0.f, red) * (1.0f / 200.0f);
  const float dv = (tid < 200) ? (v1 - mean1) : 0.f;
  const float var1 = block_sum256(dv * dv, red) * (1.0f / 200.0f);
  if (tid < 200) {
    const float y = (v1 - mean1) * rsqrtf(var1 + 1e-3f) * g1[tid] + be1[tid];
    h1[tid] = fmaxf(y, 0.f);
  }
  __syncthreads();

  float v2 = 0.f;
  if (tid < 80) {
    v2 = b2[tid];
    for (int i4 = 0; i4 < 50; ++i4) {
      const float4 xv = *(const float4*)(h1 + i4 * 4);
      const float* w = W2 + i4 * 4 * 80 + tid;
      v2 += xv.x * w[0];
      v2 += xv.y * w[80];
      v2 += xv.z * w[160];
      v2 += xv.w * w[240];
    }
  }
  const float mean2 = block_sum256((tid < 80) ? v2 : 0.f, red) * (1.0f / 80.0f);
  const float dv2 = (tid < 80) ? (v2 - mean2) : 0.f;
  const float var2 = block_sum256(dv2 * dv2, red) * (1.0f / 80.0f);
  if (tid < 80) {
    const float y = (v2 - mean2) * rsqrtf(var2 + 1e-3f) * g2[tid] + be2[tid];
    h2[tid] = fmaxf(y, 0.f);
  }
  __syncthreads();

  const float p = (tid < 80) ? h2[tid] * W3[tid] : 0.f;
  const float z = block_sum256(p, red);
  if (tid == 0) {
    out[b] = 1.0f / (1.0f + expf(-(z + b3[0])));
  }
}

// ---------------------------------------------------------------------------
extern "C" void kernel_launch(void* const* d_in, const int* in_sizes, int n_in,
                              void* d_out, int out_size, void* d_ws, size_t ws_size,
                              hipStream_t stream) {
  (void)in_sizes; (void)n_in; (void)out_size; (void)ws_size;
  const int* uid = (const int*)d_in[0];
  const int* u1  = (const int*)d_in[1];
  const int* u2  = (const int*)d_in[2];
  const int* u3  = (const int*)d_in[3];
  const int* u4  = (const int*)d_in[4];
  const int* ig  = (const int*)d_in[5];
  const int* ish = (const int*)d_in[6];
  const int* ici = (const int*)d_in[7];
  const int* sg  = (const int*)d_in[8];
  const int* ss  = (const int*)d_in[9];
  const int* scd = (const int*)d_in[10];
  const int* lg  = (const int*)d_in[11];
  const int* ls  = (const int*)d_in[12];
  const int* lcd = (const int*)d_in[13];
  const float* emb = (const float*)d_in[14];
  const float* Hm  = (const float*)d_in[15];
  const float* sWq = (const float*)d_in[16];
  const float* sbq = (const float*)d_in[17];
  const float* sWk = (const float*)d_in[18];
  const float* sbk = (const float*)d_in[19];
  const float* sWv = (const float*)d_in[20];
  const float* sbv = (const float*)d_in[21];
  const float* sWo = (const float*)d_in[22];
  const float* sbo = (const float*)d_in[23];
  const float* lWq = (const float*)d_in[24];
  const float* lbq = (const float*)d_in[25];
  const float* lWk = (const float*)d_in[26];
  const float* lbk = (const float*)d_in[27];
  const float* lWv = (const float*)d_in[28];
  const float* lbv = (const float*)d_in[29];
  const float* lWo = (const float*)d_in[30];
  const float* lbo = (const float*)d_in[31];
  const float* W1 = (const float*)d_in[32];
  const float* b1 = (const float*)d_in[33];
  const float* g1 = (const float*)d_in[34];
  const float* be1 = (const float*)d_in[35];
  const float* W2 = (const float*)d_in[36];
  const float* b2 = (const float*)d_in[37];
  const float* g2 = (const float*)d_in[38];
  const float* be2 = (const float*)d_in[39];
  const float* W3 = (const float*)d_in[40];
  const float* b3 = (const float*)d_in[41];
  float* out = (float*)d_out;

  // workspace: [gsc i8: BB*LLx = 2MB][sint: BB*48 f32]
  signed char* gsc = (signed char*)d_ws;
  float* sint = (float*)((char*)d_ws + (size_t)BB * LLx);

  k_score_short<<<dim3(9216), dim3(256), 0, stream>>>(
      lg, ls, lcd, sg, ss, scd, ig, ish, ici, emb, Hm,
      sWq, sbq, sWk, sbk, sWv, sbv, sWo, sbo, gsc, sint);
  k_long_mlp<<<dim3(BB), dim3(256), 0, stream>>>(
      lg, ls, lcd, ig, ish, ici,
      uid, u1, u2, u3, u4, emb,
      lWq, lbq, lWk, lbk, lWv, lbv, lWo, lbo,
      gsc, sint,
      W1, b1, g1, be1, W2, b2, g2, be2, W3, b3, out);
}

// Round 10
// 317.721 us; speedup vs baseline: 1.2134x; 1.2134x over previous
//
#include <hip/hip_runtime.h>
#include <math.h>

#define BB 1024
#define LSx 128
#define LLx 2048
#define TOPKx 48

// ---------------------------------------------------------------------------
// Kernel 1: long-term LSH scoring (VERBATIM R6 verified 80us version).
// ---------------------------------------------------------------------------
__global__ __launch_bounds__(256, 2) void k_score(
    const int* __restrict__ lg, const int* __restrict__ lsh, const int* __restrict__ lc,
    const int* __restrict__ ig, const int* __restrict__ ish, const int* __restrict__ ici,
    const float* __restrict__ emb, const float* __restrict__ Hm,
    signed char* __restrict__ gsc)
{
  __shared__ float Xitem[48];
  __shared__ int icode[16];
  __shared__ __align__(16) float4 xsh[256][5];   // slot 4 = pad -> 20-word stride
  const int b = blockIdx.y, tid = threadIdx.x;

  const int l = blockIdx.x * 256 + tid;
  const size_t off = (size_t)b * LLx + l;
  const int gid = lg[off];

  if (tid < 48) {
    const int seg = tid >> 4, e = tid & 15;
    const int id = (seg == 0) ? ig[b] : (seg == 1) ? ish[b] : ici[b];
    Xitem[tid] = emb[(size_t)id * 16 + e];
  }
  __syncthreads();
  if (tid < 16) {
    float dd = 0.f;
    for (int e = 0; e < 48; ++e) dd += Xitem[e] * Hm[e * 16 + tid];
    icode[tid] = (dd > 0.f) ? 1 : (dd < 0.f ? -1 : 0);
  }

  const int srow = tid >> 2;
  const int q = tid & 3;
  const size_t bbase = (size_t)b * LLx + (size_t)blockIdx.x * 256;

  float d[16];
  #pragma unroll
  for (int m = 0; m < 16; ++m) d[m] = 0.f;

  #pragma unroll
  for (int seg = 0; seg < 3; ++seg) {
    const int* idarr = (seg == 0) ? lg : (seg == 1) ? lsh : lc;
    #pragma unroll
    for (int jj = 0; jj < 4; ++jj) {
      const int pos = jj * 64 + srow;
      const int id = idarr[bbase + pos];
      xsh[pos][q] = *(const float4*)(emb + (size_t)id * 16 + q * 4);
    }
    __syncthreads();
    if (gid != 0) {
      float x[16];
      #pragma unroll
      for (int qq = 0; qq < 4; ++qq) {
        const float4 r = xsh[tid][qq];
        x[qq * 4 + 0] = r.x; x[qq * 4 + 1] = r.y;
        x[qq * 4 + 2] = r.z; x[qq * 4 + 3] = r.w;
      }
      const float* hb = Hm + seg * 256;
      #pragma unroll
      for (int i = 0; i < 16; ++i) {
        const float xi = x[i];
        #pragma unroll
        for (int mc = 0; mc < 4; ++mc) {
          const float4 h4 = *(const float4*)(hb + i * 16 + mc * 4);
          d[mc * 4 + 0] += xi * h4.x;
          d[mc * 4 + 1] += xi * h4.y;
          d[mc * 4 + 2] += xi * h4.z;
          d[mc * 4 + 3] += xi * h4.w;
        }
      }
    }
    if (seg < 2) __syncthreads();
  }

  int sc = -1;
  if (gid != 0) {
    sc = 0;
    #pragma unroll
    for (int m = 0; m < 16; ++m) {
      const int cs = (d[m] > 0.f) ? 1 : (d[m] < 0.f ? -1 : 0);
      sc += (cs == icode[m]) ? 1 : 0;
    }
  }
  gsc[off] = (signed char)sc;
}

// ---------------------------------------------------------------------------
// Kernel 2: top-k selection (VERBATIM R6 verified).
// ---------------------------------------------------------------------------
__global__ __launch_bounds__(256) void k_topk(
    const signed char* __restrict__ gsc, int* __restrict__ sel)
{
  __shared__ int hist[18];
  __shared__ int cnt_above;
  __shared__ int wsum[4];
  const int b = blockIdx.x, tid = threadIdx.x;

  const int2 myv = ((const int2*)(gsc + (size_t)b * LLx))[tid];
  signed char loc[8];
  *(int2*)loc = myv;

  if (tid < 18) hist[tid] = 0;
  if (tid == 0) cnt_above = 0;
  __syncthreads();

  #pragma unroll
  for (int j = 0; j < 8; ++j) atomicAdd(&hist[(int)loc[j] + 1], 1);
  __syncthreads();

  int above = 0, tval = -1, need = 0;
  for (int s = 16; s >= -1; --s) {
    const int c = hist[s + 1];
    if (above + c >= TOPKx) { tval = s; need = TOPKx - above; break; }
    above += c;
  }

  const int base_l = tid * (LLx / 256);
  int cnt = 0;
  #pragma unroll
  for (int j = 0; j < 8; ++j) cnt += ((int)loc[j] == tval) ? 1 : 0;
  int v = cnt;
  const int lane = tid & 63, wave = tid >> 6;
  #pragma unroll
  for (int o = 1; o < 64; o <<= 1) {
    const int u = __shfl_up(v, o, 64);
    if (lane >= o) v += u;
  }
  if (lane == 63) wsum[wave] = v;
  __syncthreads();
  int rank = v - cnt;
  for (int w = 0; w < wave; ++w) rank += wsum[w];

  #pragma unroll
  for (int j = 0; j < 8; ++j) {
    const int l = base_l + j;
    const int s = (int)loc[j];
    if (s > tval) {
      const int slot = atomicAdd(&cnt_above, 1);
      sel[b * TOPKx + slot] = l;
    } else if (s == tval) {
      if (rank < need) sel[b * TOPKx + above + rank] = l;
      ++rank;
    }
  }
}

// ---------------------------------------------------------------------------
// Kernel 3: short-MHA, PER-HEAD blocks. Grid (BB, 8), 128 threads.
// Block (b,h) computes head h only: per-column chains (e-ascending), the
// 16-lane strided softmax, and the sequential-k PV are VERBATIM slices of the
// verified 128-thread kernel -> bit-identical osm values. 8x more blocks ->
// latency hidden by TLP instead of stalling 4 blocks/CU.
// ---------------------------------------------------------------------------
__global__ __launch_bounds__(128) void k_mha_short_h(
    const int* __restrict__ kg, const int* __restrict__ ks, const int* __restrict__ kc,
    const int* __restrict__ ig, const int* __restrict__ ish, const int* __restrict__ ici,
    const float* __restrict__ emb,
    const float* __restrict__ Wq, const float* __restrict__ bq,
    const float* __restrict__ Wk, const float* __restrict__ bk,
    const float* __restrict__ Wv, const float* __restrict__ bv,
    float* __restrict__ osm_g)
{
  __shared__ float Xitem[48];
  __shared__ float qh[6];
  __shared__ float scs[LSx];
  __shared__ float vhT[6][LSx + 4];
  __shared__ unsigned char validf[LSx];
  const int b = blockIdx.x, h = blockIdx.y, tid = threadIdx.x;

  if (tid < 48) {
    const int seg = tid >> 4, e = tid & 15;
    const int id = (seg == 0) ? ig[b] : (seg == 1) ? ish[b] : ici[b];
    Xitem[tid] = emb[(size_t)id * 16 + e];
  }
  __syncthreads();
  if (tid < 6) {
    const int col = h * 6 + tid;
    float a = bq[col];
    for (int e = 0; e < 48; ++e) a += Xitem[e] * Wq[e * 48 + col];
    qh[tid] = a;
  }

  int gid, sid, cid;
  {
    const size_t off = (size_t)b * LSx + tid;
    gid = kg[off]; sid = ks[off]; cid = kc[off];
  }
  const int nval = __syncthreads_count(gid != 0);   // also publishes qh

  {
    validf[tid] = (unsigned char)(tid < nval);      // short mask: pos < slen
    float kh[6], vh[6];
    #pragma unroll
    for (int j = 0; j < 6; ++j) { kh[j] = bk[h * 6 + j]; vh[j] = bv[h * 6 + j]; }
    const int ids3[3] = {gid, sid, cid};
    #pragma unroll
    for (int seg = 0; seg < 3; ++seg) {
      const float* row = emb + (size_t)ids3[seg] * 16;
      #pragma unroll
      for (int i4 = 0; i4 < 4; ++i4) {
        const float4 xv = ((const float4*)row)[i4];
        const float xs[4] = {xv.x, xv.y, xv.z, xv.w};
        #pragma unroll
        for (int c = 0; c < 4; ++c) {
          const int e = seg * 16 + i4 * 4 + c;
          const float* wkr = Wk + e * 48 + h * 6;   // uniform -> scalar loads
          const float* wvr = Wv + e * 48 + h * 6;
          const float xe = xs[c];
          #pragma unroll
          for (int j = 0; j < 6; ++j) {
            kh[j] += xe * wkr[j];
            vh[j] += xe * wvr[j];
          }
        }
      }
    }
    float s = 0.f;
    #pragma unroll
    for (int d = 0; d < 6; ++d) s += qh[d] * kh[d];
    scs[tid] = s * 0.40824829046386301637f;         // 1/sqrt(6)
    #pragma unroll
    for (int j = 0; j < 6; ++j) vhT[j][tid] = vh[j];
  }
  __syncthreads();

  // ---- softmax: lanes 0..15 replicate the verified 16-lane group ----
  if (tid < 16) {
    const int l16 = tid;
    float amax = -INFINITY;
    for (int k = l16; k < LSx; k += 16) if (validf[k]) amax = fmaxf(amax, scs[k]);
    #pragma unroll
    for (int m = 1; m < 16; m <<= 1) amax = fmaxf(amax, __shfl_xor(amax, m, 16));
    if (nval == 0) {
      for (int k = l16; k < LSx; k += 16) scs[k] = 1.0f / (float)LSx;
    } else {
      float ssum = 0.f;
      for (int k = l16; k < LSx; k += 16) {
        const float ev = validf[k] ? expf(scs[k] - amax) : 0.f;
        scs[k] = ev;
        ssum += ev;
      }
      #pragma unroll
      for (int m = 1; m < 16; m <<= 1) ssum += __shfl_xor(ssum, m, 16);
      const float inv = 1.0f / ssum;
      for (int k = l16; k < LSx; k += 16) scs[k] *= inv;
    }
  }
  __syncthreads();

  // ---- PV: 6 threads, sequential k (verbatim order) ----
  if (tid < 6) {
    float a = 0.f;
    for (int k = 0; k < LSx; ++k) a += scs[k] * vhT[tid][k];
    osm_g[b * 48 + h * 6 + tid] = a;
  }
}

// ---------------------------------------------------------------------------
// Kernel 4: long-MHA, PER-HEAD blocks. Grid (BB, 8), 64 threads (1 wave).
// Same verbatim-slice construction over the 48 selected keys.
// ---------------------------------------------------------------------------
__global__ __launch_bounds__(64) void k_mha_long_h(
    const int* __restrict__ kg, const int* __restrict__ ks, const int* __restrict__ kc,
    const int* __restrict__ ig, const int* __restrict__ ish, const int* __restrict__ ici,
    const float* __restrict__ emb,
    const float* __restrict__ Wq, const float* __restrict__ bq,
    const float* __restrict__ Wk, const float* __restrict__ bk,
    const float* __restrict__ Wv, const float* __restrict__ bv,
    const int* __restrict__ sel,
    float* __restrict__ osm_g)
{
  __shared__ float Xitem[48];
  __shared__ float qh[6];
  __shared__ float scs[TOPKx];
  __shared__ float vhT[6][TOPKx + 4];
  __shared__ unsigned char validf[TOPKx];
  const int b = blockIdx.x, h = blockIdx.y, tid = threadIdx.x;

  if (tid < 48) {
    const int seg = tid >> 4, e = tid & 15;
    const int id = (seg == 0) ? ig[b] : (seg == 1) ? ish[b] : ici[b];
    Xitem[tid] = emb[(size_t)id * 16 + e];
  }
  __syncthreads();
  if (tid < 6) {
    const int col = h * 6 + tid;
    float a = bq[col];
    for (int e = 0; e < 48; ++e) a += Xitem[e] * Wq[e * 48 + col];
    qh[tid] = a;
  }

  int gid = 0, sid = 0, cid = 0;
  if (tid < TOPKx) {
    const int pos = sel[b * TOPKx + tid];
    const size_t off = (size_t)b * LLx + pos;
    gid = kg[off]; sid = ks[off]; cid = kc[off];
  }
  const int nval = __syncthreads_count((tid < TOPKx) && (gid != 0));

  if (tid < TOPKx) {
    validf[tid] = (unsigned char)(gid != 0);        // long mask: gid != 0
    float kh[6], vh[6];
    #pragma unroll
    for (int j = 0; j < 6; ++j) { kh[j] = bk[h * 6 + j]; vh[j] = bv[h * 6 + j]; }
    const int ids3[3] = {gid, sid, cid};
    #pragma unroll
    for (int seg = 0; seg < 3; ++seg) {
      const float* row = emb + (size_t)ids3[seg] * 16;
      #pragma unroll
      for (int i4 = 0; i4 < 4; ++i4) {
        const float4 xv = ((const float4*)row)[i4];
        const float xs[4] = {xv.x, xv.y, xv.z, xv.w};
        #pragma unroll
        for (int c = 0; c < 4; ++c) {
          const int e = seg * 16 + i4 * 4 + c;
          const float* wkr = Wk + e * 48 + h * 6;
          const float* wvr = Wv + e * 48 + h * 6;
          const float xe = xs[c];
          #pragma unroll
          for (int j = 0; j < 6; ++j) {
            kh[j] += xe * wkr[j];
            vh[j] += xe * wvr[j];
          }
        }
      }
    }
    float s = 0.f;
    #pragma unroll
    for (int d = 0; d < 6; ++d) s += qh[d] * kh[d];
    scs[tid] = s * 0.40824829046386301637f;
    #pragma unroll
    for (int j = 0; j < 6; ++j) vhT[j][tid] = vh[j];
  }
  __syncthreads();

  if (tid < 16) {
    const int l16 = tid;
    float amax = -INFINITY;
    for (int k = l16; k < TOPKx; k += 16) if (validf[k]) amax = fmaxf(amax, scs[k]);
    #pragma unroll
    for (int m = 1; m < 16; m <<= 1) amax = fmaxf(amax, __shfl_xor(amax, m, 16));
    if (nval == 0) {
      for (int k = l16; k < TOPKx; k += 16) scs[k] = 1.0f / (float)TOPKx;
    } else {
      float ssum = 0.f;
      for (int k = l16; k < TOPKx; k += 16) {
        const float ev = validf[k] ? expf(scs[k] - amax) : 0.f;
        scs[k] = ev;
        ssum += ev;
      }
      #pragma unroll
      for (int m = 1; m < 16; m <<= 1) ssum += __shfl_xor(ssum, m, 16);
      const float inv = 1.0f / ssum;
      for (int k = l16; k < TOPKx; k += 16) scs[k] *= inv;
    }
  }
  __syncthreads();

  if (tid < 6) {
    float a = 0.f;
    for (int k = 0; k < TOPKx; ++k) a += scs[k] * vhT[tid][k];
    osm_g[b * 48 + h * 6 + tid] = a;
  }
}

// ---------------------------------------------------------------------------
// Kernel 5: output projections + MLP head. One 256-thread block per batch.
// Out-proj chains and MLP body VERBATIM from verified kernels.
// ---------------------------------------------------------------------------
__device__ __forceinline__ float block_sum256(float v, float* red) {
  #pragma unroll
  for (int m = 32; m >= 1; m >>= 1) v += __shfl_xor(v, m, 64);
  const int lane = threadIdx.x & 63, wave = threadIdx.x >> 6;
  if (lane == 0) red[wave] = v;
  __syncthreads();
  const float t = red[0] + red[1] + red[2] + red[3];
  __syncthreads();
  return t;
}

__global__ __launch_bounds__(256) void k_mlp(
    const int* __restrict__ uid, const int* __restrict__ u1, const int* __restrict__ u2,
    const int* __restrict__ u3, const int* __restrict__ u4,
    const int* __restrict__ ig, const int* __restrict__ ish, const int* __restrict__ ici,
    const float* __restrict__ emb,
    const float* __restrict__ osm_s, const float* __restrict__ osm_l,
    const float* __restrict__ sWo, const float* __restrict__ sbo,
    const float* __restrict__ lWo, const float* __restrict__ lbo,
    const float* __restrict__ W1, const float* __restrict__ b1,
    const float* __restrict__ g1, const float* __restrict__ be1,
    const float* __restrict__ W2, const float* __restrict__ b2,
    const float* __restrict__ g2, const float* __restrict__ be2,
    const float* __restrict__ W3, const float* __restrict__ b3,
    float* __restrict__ out)
{
  __shared__ __align__(16) float x[224];
  __shared__ __align__(16) float h1[200];
  __shared__ float h2[80];
  __shared__ float red[4];
  __shared__ float osm_sl[48], osm_ll[48];
  const int b = blockIdx.x, tid = threadIdx.x;

  if (tid < 128) {
    const int e = tid & 15;
    int id;
    if (tid < 48) {
      const int seg = tid >> 4;
      id = (seg == 0) ? ig[b] : (seg == 1) ? ish[b] : ici[b];
    } else {
      const int f = (tid - 48) >> 4;
      id = (f == 0) ? uid[b] : (f == 1) ? u1[b] : (f == 2) ? u2[b] : (f == 3) ? u3[b] : u4[b];
    }
    x[tid] = emb[(size_t)id * 16 + e];
  } else if (tid < 176) {
    osm_sl[tid - 128] = osm_s[b * 48 + (tid - 128)];
  } else if (tid < 224) {
    osm_ll[tid - 176] = osm_l[b * 48 + (tid - 176)];
  }
  __syncthreads();

  // ---- output projections (verbatim chains) ----
  if (tid < 48) {
    float r = sbo[tid];
    for (int j = 0; j < 48; ++j) r += osm_sl[j] * sWo[j * 48 + tid];
    x[128 + tid] = r;
  } else if (tid >= 64 && tid < 112) {
    const int c = tid - 64;
    float r = lbo[c];
    for (int j = 0; j < 48; ++j) r += osm_ll[j] * lWo[j * 48 + c];
    x[176 + c] = r;
  }
  __syncthreads();

  float v = 0.f;
  if (tid < 200) {
    v = b1[tid];
    for (int i4 = 0; i4 < 56; ++i4) {
      const float4 xv = *(const float4*)(x + i4 * 4);
      const float* w = W1 + i4 * 4 * 200 + tid;
      v += xv.x * w[0];
      v += xv.y * w[200];
      v += xv.z * w[400];
      v += xv.w * w[600];
    }
  }
  const float mean1 = block_sum256((tid < 200) ? v : 0.f, red) * (1.0f / 200.0f);
  const float dv = (tid < 200) ? (v - mean1) : 0.f;
  const float var1 = block_sum256(dv * dv, red) * (1.0f / 200.0f);
  if (tid < 200) {
    const float y = (v - mean1) * rsqrtf(var1 + 1e-3f) * g1[tid] + be1[tid];
    h1[tid] = fmaxf(y, 0.f);
  }
  __syncthreads();

  float v2 = 0.f;
  if (tid < 80) {
    v2 = b2[tid];
    for (int i4 = 0; i4 < 50; ++i4) {
      const float4 xv = *(const float4*)(h1 + i4 * 4);
      const float* w = W2 + i4 * 4 * 80 + tid;
      v2 += xv.x * w[0];
      v2 += xv.y * w[80];
      v2 += xv.z * w[160];
      v2 += xv.w * w[240];
    }
  }
  const float mean2 = block_sum256((tid < 80) ? v2 : 0.f, red) * (1.0f / 80.0f);
  const float dv2 = (tid < 80) ? (v2 - mean2) : 0.f;
  const float var2 = block_sum256(dv2 * dv2, red) * (1.0f / 80.0f);
  if (tid < 80) {
    const float y = (v2 - mean2) * rsqrtf(var2 + 1e-3f) * g2[tid] + be2[tid];
    h2[tid] = fmaxf(y, 0.f);
  }
  __syncthreads();

  const float p = (tid < 80) ? h2[tid] * W3[tid] : 0.f;
  const float z = block_sum256(p, red);
  if (tid == 0) {
    out[b] = 1.0f / (1.0f + expf(-(z + b3[0])));
  }
}

// ---------------------------------------------------------------------------
extern "C" void kernel_launch(void* const* d_in, const int* in_sizes, int n_in,
                              void* d_out, int out_size, void* d_ws, size_t ws_size,
                              hipStream_t stream) {
  (void)in_sizes; (void)n_in; (void)out_size; (void)ws_size;
  const int* uid = (const int*)d_in[0];
  const int* u1  = (const int*)d_in[1];
  const int* u2  = (const int*)d_in[2];
  const int* u3  = (const int*)d_in[3];
  const int* u4  = (const int*)d_in[4];
  const int* ig  = (const int*)d_in[5];
  const int* ish = (const int*)d_in[6];
  const int* ici = (const int*)d_in[7];
  const int* sg  = (const int*)d_in[8];
  const int* ss  = (const int*)d_in[9];
  const int* scd = (const int*)d_in[10];
  const int* lg  = (const int*)d_in[11];
  const int* ls  = (const int*)d_in[12];
  const int* lcd = (const int*)d_in[13];
  const float* emb = (const float*)d_in[14];
  const float* Hm  = (const float*)d_in[15];
  const float* sWq = (const float*)d_in[16];
  const float* sbq = (const float*)d_in[17];
  const float* sWk = (const float*)d_in[18];
  const float* sbk = (const float*)d_in[19];
  const float* sWv = (const float*)d_in[20];
  const float* sbv = (const float*)d_in[21];
  const float* sWo = (const float*)d_in[22];
  const float* sbo = (const float*)d_in[23];
  const float* lWq = (const float*)d_in[24];
  const float* lbq = (const float*)d_in[25];
  const float* lWk = (const float*)d_in[26];
  const float* lbk = (const float*)d_in[27];
  const float* lWv = (const float*)d_in[28];
  const float* lbv = (const float*)d_in[29];
  const float* lWo = (const float*)d_in[30];
  const float* lbo = (const float*)d_in[31];
  const float* W1 = (const float*)d_in[32];
  const float* b1 = (const float*)d_in[33];
  const float* g1 = (const float*)d_in[34];
  const float* be1 = (const float*)d_in[35];
  const float* W2 = (const float*)d_in[36];
  const float* b2 = (const float*)d_in[37];
  const float* g2 = (const float*)d_in[38];
  const float* be2 = (const float*)d_in[39];
  const float* W3 = (const float*)d_in[40];
  const float* b3 = (const float*)d_in[41];
  float* out = (float*)d_out;

  // workspace: [gsc 2MB][sel 192KB][osm_s 192KB][osm_l 192KB]
  signed char* gsc = (signed char*)d_ws;
  int* sel = (int*)((char*)d_ws + (size_t)BB * LLx);
  float* osm_s = (float*)(sel + BB * TOPKx);
  float* osm_l = osm_s + BB * 48;

  k_score<<<dim3(LLx / 256, BB), dim3(256), 0, stream>>>(
      lg, ls, lcd, ig, ish, ici, emb, Hm, gsc);
  k_topk<<<dim3(BB), dim3(256), 0, stream>>>(gsc, sel);
  k_mha_short_h<<<dim3(BB, 8), dim3(128), 0, stream>>>(
      sg, ss, scd, ig, ish, ici, emb,
      sWq, sbq, sWk, sbk, sWv, sbv, osm_s);
  k_mha_long_h<<<dim3(BB, 8), dim3(64), 0, stream>>>(
      lg, ls, lcd, ig, ish, ici, emb,
      lWq, lbq, lWk, lbk, lWv, lbv, sel, osm_l);
  k_mlp<<<dim3(BB), dim3(256), 0, stream>>>(
      uid, u1, u2, u3, u4, ig, ish, ici, emb,
      osm_s, osm_l, sWo, sbo, lWo, lbo,
      W1, b1, g1, be1, W2, b2, g2, be2, W3, b3, out);
}

// Round 11
// 311.037 us; speedup vs baseline: 1.2395x; 1.0215x over previous
//
#include <hip/hip_runtime.h>
#include <math.h>

#define BB 1024
#define LSx 128
#define LLx 2048
#define TOPKx 48

// ---------------------------------------------------------------------------
// Kernel 1: long-term LSH scoring. R11: 128-thread / 128-position blocks
// (was 256/256) — LDS 10.5 KB, VGPR<=128 cap -> ~15 blocks/CU x 2 waves
// = ~30 waves/CU (94%) vs 16 (50%). Seg-tiled staging, padded [5]-float4
// rows, e-ascending FMA chain all VERBATIM -> bit-identical scores.
// ---------------------------------------------------------------------------
__global__ __launch_bounds__(128, 4) void k_score(
    const int* __restrict__ lg, const int* __restrict__ lsh, const int* __restrict__ lc,
    const int* __restrict__ ig, const int* __restrict__ ish, const int* __restrict__ ici,
    const float* __restrict__ emb, const float* __restrict__ Hm,
    signed char* __restrict__ gsc)
{
  __shared__ float Xitem[48];
  __shared__ int icode[16];
  __shared__ __align__(16) float4 xsh[128][5];   // slot 4 = pad -> 20-word stride
  const int b = blockIdx.y, tid = threadIdx.x;

  const int l = blockIdx.x * 128 + tid;
  const size_t off = (size_t)b * LLx + l;
  const int gid = lg[off];

  if (tid < 48) {
    const int seg = tid >> 4, e = tid & 15;
    const int id = (seg == 0) ? ig[b] : (seg == 1) ? ish[b] : ici[b];
    Xitem[tid] = emb[(size_t)id * 16 + e];
  }
  __syncthreads();
  if (tid < 16) {
    float dd = 0.f;
    for (int e = 0; e < 48; ++e) dd += Xitem[e] * Hm[e * 16 + tid];
    icode[tid] = (dd > 0.f) ? 1 : (dd < 0.f ? -1 : 0);
    // visible after the seg-0 staging barrier; read only at the end
  }

  const int srow = tid >> 2;               // stager: row within jj-tile of 32
  const int q = tid & 3;                   // stager: 16B quarter of the row
  const size_t bbase = (size_t)b * LLx + (size_t)blockIdx.x * 128;

  float d[16];
  #pragma unroll
  for (int m = 0; m < 16; ++m) d[m] = 0.f;

  #pragma unroll
  for (int seg = 0; seg < 3; ++seg) {
    const int* idarr = (seg == 0) ? lg : (seg == 1) ? lsh : lc;
    // ---- stage this segment's 128 rows (64B coalesced per quad) ----
    #pragma unroll
    for (int jj = 0; jj < 4; ++jj) {
      const int pos = jj * 32 + srow;
      const int id = idarr[bbase + pos];   // quad-broadcast, line-coalesced
      xsh[pos][q] = *(const float4*)(emb + (size_t)id * 16 + q * 4);
    }
    __syncthreads();
    // ---- accumulate: bit-exact e-ascending chain ----
    if (gid != 0) {
      float x[16];
      #pragma unroll
      for (int qq = 0; qq < 4; ++qq) {
        const float4 r = xsh[tid][qq];     // 20-word stride: conflict-floor
        x[qq * 4 + 0] = r.x; x[qq * 4 + 1] = r.y;
        x[qq * 4 + 2] = r.z; x[qq * 4 + 3] = r.w;
      }
      const float* hb = Hm + seg * 256;    // H[e][m], e = seg*16+i
      #pragma unroll
      for (int i = 0; i < 16; ++i) {
        const float xi = x[i];
        #pragma unroll
        for (int mc = 0; mc < 4; ++mc) {
          const float4 h4 = *(const float4*)(hb + i * 16 + mc * 4);
          d[mc * 4 + 0] += xi * h4.x;
          d[mc * 4 + 1] += xi * h4.y;
          d[mc * 4 + 2] += xi * h4.z;
          d[mc * 4 + 3] += xi * h4.w;
        }
      }
    }
    if (seg < 2) __syncthreads();          // before next seg overwrites xsh
  }

  int sc = -1;                             // masked (reference: -inf)
  if (gid != 0) {
    sc = 0;
    #pragma unroll
    for (int m = 0; m < 16; ++m) {
      const int cs = (d[m] > 0.f) ? 1 : (d[m] < 0.f ? -1 : 0);
      sc += (cs == icode[m]) ? 1 : 0;
    }
  }
  gsc[off] = (signed char)sc;
}

// ---------------------------------------------------------------------------
// Kernel 2: top-k selection (VERBATIM R6 verified).
// ---------------------------------------------------------------------------
__global__ __launch_bounds__(256) void k_topk(
    const signed char* __restrict__ gsc, int* __restrict__ sel)
{
  __shared__ int hist[18];
  __shared__ int cnt_above;
  __shared__ int wsum[4];
  const int b = blockIdx.x, tid = threadIdx.x;

  const int2 myv = ((const int2*)(gsc + (size_t)b * LLx))[tid];
  signed char loc[8];
  *(int2*)loc = myv;

  if (tid < 18) hist[tid] = 0;
  if (tid == 0) cnt_above = 0;
  __syncthreads();

  #pragma unroll
  for (int j = 0; j < 8; ++j) atomicAdd(&hist[(int)loc[j] + 1], 1);
  __syncthreads();

  int above = 0, tval = -1, need = 0;
  for (int s = 16; s >= -1; --s) {
    const int c = hist[s + 1];
    if (above + c >= TOPKx) { tval = s; need = TOPKx - above; break; }
    above += c;
  }

  const int base_l = tid * (LLx / 256);
  int cnt = 0;
  #pragma unroll
  for (int j = 0; j < 8; ++j) cnt += ((int)loc[j] == tval) ? 1 : 0;
  int v = cnt;
  const int lane = tid & 63, wave = tid >> 6;
  #pragma unroll
  for (int o = 1; o < 64; o <<= 1) {
    const int u = __shfl_up(v, o, 64);
    if (lane >= o) v += u;
  }
  if (lane == 63) wsum[wave] = v;
  __syncthreads();
  int rank = v - cnt;
  for (int w = 0; w < wave; ++w) rank += wsum[w];

  #pragma unroll
  for (int j = 0; j < 8; ++j) {
    const int l = base_l + j;
    const int s = (int)loc[j];
    if (s > tval) {
      const int slot = atomicAdd(&cnt_above, 1);
      sel[b * TOPKx + slot] = l;
    } else if (s == tval) {
      if (rank < need) sel[b * TOPKx + above + rank] = l;
      ++rank;
    }
  }
}

// ---------------------------------------------------------------------------
// Kernel 3: short-MHA, PER-HEAD blocks (VERBATIM R10 verified).
// ---------------------------------------------------------------------------
__global__ __launch_bounds__(128) void k_mha_short_h(
    const int* __restrict__ kg, const int* __restrict__ ks, const int* __restrict__ kc,
    const int* __restrict__ ig, const int* __restrict__ ish, const int* __restrict__ ici,
    const float* __restrict__ emb,
    const float* __restrict__ Wq, const float* __restrict__ bq,
    const float* __restrict__ Wk, const float* __restrict__ bk,
    const float* __restrict__ Wv, const float* __restrict__ bv,
    float* __restrict__ osm_g)
{
  __shared__ float Xitem[48];
  __shared__ float qh[6];
  __shared__ float scs[LSx];
  __shared__ float vhT[6][LSx + 4];
  __shared__ unsigned char validf[LSx];
  const int b = blockIdx.x, h = blockIdx.y, tid = threadIdx.x;

  if (tid < 48) {
    const int seg = tid >> 4, e = tid & 15;
    const int id = (seg == 0) ? ig[b] : (seg == 1) ? ish[b] : ici[b];
    Xitem[tid] = emb[(size_t)id * 16 + e];
  }
  __syncthreads();
  if (tid < 6) {
    const int col = h * 6 + tid;
    float a = bq[col];
    for (int e = 0; e < 48; ++e) a += Xitem[e] * Wq[e * 48 + col];
    qh[tid] = a;
  }

  int gid, sid, cid;
  {
    const size_t off = (size_t)b * LSx + tid;
    gid = kg[off]; sid = ks[off]; cid = kc[off];
  }
  const int nval = __syncthreads_count(gid != 0);   // also publishes qh

  {
    validf[tid] = (unsigned char)(tid < nval);      // short mask: pos < slen
    float kh[6], vh[6];
    #pragma unroll
    for (int j = 0; j < 6; ++j) { kh[j] = bk[h * 6 + j]; vh[j] = bv[h * 6 + j]; }
    const int ids3[3] = {gid, sid, cid};
    #pragma unroll
    for (int seg = 0; seg < 3; ++seg) {
      const float* row = emb + (size_t)ids3[seg] * 16;
      #pragma unroll
      for (int i4 = 0; i4 < 4; ++i4) {
        const float4 xv = ((const float4*)row)[i4];
        const float xs[4] = {xv.x, xv.y, xv.z, xv.w};
        #pragma unroll
        for (int c = 0; c < 4; ++c) {
          const int e = seg * 16 + i4 * 4 + c;
          const float* wkr = Wk + e * 48 + h * 6;   // uniform -> scalar loads
          const float* wvr = Wv + e * 48 + h * 6;
          const float xe = xs[c];
          #pragma unroll
          for (int j = 0; j < 6; ++j) {
            kh[j] += xe * wkr[j];
            vh[j] += xe * wvr[j];
          }
        }
      }
    }
    float s = 0.f;
    #pragma unroll
    for (int d = 0; d < 6; ++d) s += qh[d] * kh[d];
    scs[tid] = s * 0.40824829046386301637f;         // 1/sqrt(6)
    #pragma unroll
    for (int j = 0; j < 6; ++j) vhT[j][tid] = vh[j];
  }
  __syncthreads();

  // ---- softmax: lanes 0..15 replicate the verified 16-lane group ----
  if (tid < 16) {
    const int l16 = tid;
    float amax = -INFINITY;
    for (int k = l16; k < LSx; k += 16) if (validf[k]) amax = fmaxf(amax, scs[k]);
    #pragma unroll
    for (int m = 1; m < 16; m <<= 1) amax = fmaxf(amax, __shfl_xor(amax, m, 16));
    if (nval == 0) {
      for (int k = l16; k < LSx; k += 16) scs[k] = 1.0f / (float)LSx;
    } else {
      float ssum = 0.f;
      for (int k = l16; k < LSx; k += 16) {
        const float ev = validf[k] ? expf(scs[k] - amax) : 0.f;
        scs[k] = ev;
        ssum += ev;
      }
      #pragma unroll
      for (int m = 1; m < 16; m <<= 1) ssum += __shfl_xor(ssum, m, 16);
      const float inv = 1.0f / ssum;
      for (int k = l16; k < LSx; k += 16) scs[k] *= inv;
    }
  }
  __syncthreads();

  // ---- PV: 6 threads, sequential k (verbatim order) ----
  if (tid < 6) {
    float a = 0.f;
    for (int k = 0; k < LSx; ++k) a += scs[k] * vhT[tid][k];
    osm_g[b * 48 + h * 6 + tid] = a;
  }
}

// ---------------------------------------------------------------------------
// Kernel 4: long-MHA, PER-HEAD blocks (VERBATIM R10 verified).
// ---------------------------------------------------------------------------
__global__ __launch_bounds__(64) void k_mha_long_h(
    const int* __restrict__ kg, const int* __restrict__ ks, const int* __restrict__ kc,
    const int* __restrict__ ig, const int* __restrict__ ish, const int* __restrict__ ici,
    const float* __restrict__ emb,
    const float* __restrict__ Wq, const float* __restrict__ bq,
    const float* __restrict__ Wk, const float* __restrict__ bk,
    const float* __restrict__ Wv, const float* __restrict__ bv,
    const int* __restrict__ sel,
    float* __restrict__ osm_g)
{
  __shared__ float Xitem[48];
  __shared__ float qh[6];
  __shared__ float scs[TOPKx];
  __shared__ float vhT[6][TOPKx + 4];
  __shared__ unsigned char validf[TOPKx];
  const int b = blockIdx.x, h = blockIdx.y, tid = threadIdx.x;

  if (tid < 48) {
    const int seg = tid >> 4, e = tid & 15;
    const int id = (seg == 0) ? ig[b] : (seg == 1) ? ish[b] : ici[b];
    Xitem[tid] = emb[(size_t)id * 16 + e];
  }
  __syncthreads();
  if (tid < 6) {
    const int col = h * 6 + tid;
    float a = bq[col];
    for (int e = 0; e < 48; ++e) a += Xitem[e] * Wq[e * 48 + col];
    qh[tid] = a;
  }

  int gid = 0, sid = 0, cid = 0;
  if (tid < TOPKx) {
    const int pos = sel[b * TOPKx + tid];
    const size_t off = (size_t)b * LLx + pos;
    gid = kg[off]; sid = ks[off]; cid = kc[off];
  }
  const int nval = __syncthreads_count((tid < TOPKx) && (gid != 0));

  if (tid < TOPKx) {
    validf[tid] = (unsigned char)(gid != 0);        // long mask: gid != 0
    float kh[6], vh[6];
    #pragma unroll
    for (int j = 0; j < 6; ++j) { kh[j] = bk[h * 6 + j]; vh[j] = bv[h * 6 + j]; }
    const int ids3[3] = {gid, sid, cid};
    #pragma unroll
    for (int seg = 0; seg < 3; ++seg) {
      const float* row = emb + (size_t)ids3[seg] * 16;
      #pragma unroll
      for (int i4 = 0; i4 < 4; ++i4) {
        const float4 xv = ((const float4*)row)[i4];
        const float xs[4] = {xv.x, xv.y, xv.z, xv.w};
        #pragma unroll
        for (int c = 0; c < 4; ++c) {
          const int e = seg * 16 + i4 * 4 + c;
          const float* wkr = Wk + e * 48 + h * 6;
          const float* wvr = Wv + e * 48 + h * 6;
          const float xe = xs[c];
          #pragma unroll
          for (int j = 0; j < 6; ++j) {
            kh[j] += xe * wkr[j];
            vh[j] += xe * wvr[j];
          }
        }
      }
    }
    float s = 0.f;
    #pragma unroll
    for (int d = 0; d < 6; ++d) s += qh[d] * kh[d];
    scs[tid] = s * 0.40824829046386301637f;
    #pragma unroll
    for (int j = 0; j < 6; ++j) vhT[j][tid] = vh[j];
  }
  __syncthreads();

  if (tid < 16) {
    const int l16 = tid;
    float amax = -INFINITY;
    for (int k = l16; k < TOPKx; k += 16) if (validf[k]) amax = fmaxf(amax, scs[k]);
    #pragma unroll
    for (int m = 1; m < 16; m <<= 1) amax = fmaxf(amax, __shfl_xor(amax, m, 16));
    if (nval == 0) {
      for (int k = l16; k < TOPKx; k += 16) scs[k] = 1.0f / (float)TOPKx;
    } else {
      float ssum = 0.f;
      for (int k = l16; k < TOPKx; k += 16) {
        const float ev = validf[k] ? expf(scs[k] - amax) : 0.f;
        scs[k] = ev;
        ssum += ev;
      }
      #pragma unroll
      for (int m = 1; m < 16; m <<= 1) ssum += __shfl_xor(ssum, m, 16);
      const float inv = 1.0f / ssum;
      for (int k = l16; k < TOPKx; k += 16) scs[k] *= inv;
    }
  }
  __syncthreads();

  if (tid < 6) {
    float a = 0.f;
    for (int k = 0; k < TOPKx; ++k) a += scs[k] * vhT[tid][k];
    osm_g[b * 48 + h * 6 + tid] = a;
  }
}

// ---------------------------------------------------------------------------
// Kernel 5: output projections + MLP head (VERBATIM R10 verified).
// ---------------------------------------------------------------------------
__device__ __forceinline__ float block_sum256(float v, float* red) {
  #pragma unroll
  for (int m = 32; m >= 1; m >>= 1) v += __shfl_xor(v, m, 64);
  const int lane = threadIdx.x & 63, wave = threadIdx.x >> 6;
  if (lane == 0) red[wave] = v;
  __syncthreads();
  const float t = red[0] + red[1] + red[2] + red[3];
  __syncthreads();
  return t;
}

__global__ __launch_bounds__(256) void k_mlp(
    const int* __restrict__ uid, const int* __restrict__ u1, const int* __restrict__ u2,
    const int* __restrict__ u3, const int* __restrict__ u4,
    const int* __restrict__ ig, const int* __restrict__ ish, const int* __restrict__ ici,
    const float* __restrict__ emb,
    const float* __restrict__ osm_s, const float* __restrict__ osm_l,
    const float* __restrict__ sWo, const float* __restrict__ sbo,
    const float* __restrict__ lWo, const float* __restrict__ lbo,
    const float* __restrict__ W1, const float* __restrict__ b1,
    const float* __restrict__ g1, const float* __restrict__ be1,
    const float* __restrict__ W2, const float* __restrict__ b2,
    const float* __restrict__ g2, const float* __restrict__ be2,
    const float* __restrict__ W3, const float* __restrict__ b3,
    float* __restrict__ out)
{
  __shared__ __align__(16) float x[224];
  __shared__ __align__(16) float h1[200];
  __shared__ float h2[80];
  __shared__ float red[4];
  __shared__ float osm_sl[48], osm_ll[48];
  const int b = blockIdx.x, tid = threadIdx.x;

  if (tid < 128) {
    const int e = tid & 15;
    int id;
    if (tid < 48) {
      const int seg = tid >> 4;
      id = (seg == 0) ? ig[b] : (seg == 1) ? ish[b] : ici[b];
    } else {
      const int f = (tid - 48) >> 4;
      id = (f == 0) ? uid[b] : (f == 1) ? u1[b] : (f == 2) ? u2[b] : (f == 3) ? u3[b] : u4[b];
    }
    x[tid] = emb[(size_t)id * 16 + e];
  } else if (tid < 176) {
    osm_sl[tid - 128] = osm_s[b * 48 + (tid - 128)];
  } else if (tid < 224) {
    osm_ll[tid - 176] = osm_l[b * 48 + (tid - 176)];
  }
  __syncthreads();

  // ---- output projections (verbatim chains) ----
  if (tid < 48) {
    float r = sbo[tid];
    for (int j = 0; j < 48; ++j) r += osm_sl[j] * sWo[j * 48 + tid];
    x[128 + tid] = r;
  } else if (tid >= 64 && tid < 112) {
    const int c = tid - 64;
    float r = lbo[c];
    for (int j = 0; j < 48; ++j) r += osm_ll[j] * lWo[j * 48 + c];
    x[176 + c] = r;
  }
  __syncthreads();

  float v = 0.f;
  if (tid < 200) {
    v = b1[tid];
    for (int i4 = 0; i4 < 56; ++i4) {
      const float4 xv = *(const float4*)(x + i4 * 4);
      const float* w = W1 + i4 * 4 * 200 + tid;
      v += xv.x * w[0];
      v += xv.y * w[200];
      v += xv.z * w[400];
      v += xv.w * w[600];
    }
  }
  const float mean1 = block_sum256((tid < 200) ? v : 0.f, red) * (1.0f / 200.0f);
  const float dv = (tid < 200) ? (v - mean1) : 0.f;
  const float var1 = block_sum256(dv * dv, red) * (1.0f / 200.0f);
  if (tid < 200) {
    const float y = (v - mean1) * rsqrtf(var1 + 1e-3f) * g1[tid] + be1[tid];
    h1[tid] = fmaxf(y, 0.f);
  }
  __syncthreads();

  float v2 = 0.f;
  if (tid < 80) {
    v2 = b2[tid];
    for (int i4 = 0; i4 < 50; ++i4) {
      const float4 xv = *(const float4*)(h1 + i4 * 4);
      const float* w = W2 + i4 * 4 * 80 + tid;
      v2 += xv.x * w[0];
      v2 += xv.y * w[80];
      v2 += xv.z * w[160];
      v2 += xv.w * w[240];
    }
  }
  const float mean2 = block_sum256((tid < 80) ? v2 : 0.f, red) * (1.0f / 80.0f);
  const float dv2 = (tid < 80) ? (v2 - mean2) : 0.f;
  const float var2 = block_sum256(dv2 * dv2, red) * (1.0f / 80.0f);
  if (tid < 80) {
    const float y = (v2 - mean2) * rsqrtf(var2 + 1e-3f) * g2[tid] + be2[tid];
    h2[tid] = fmaxf(y, 0.f);
  }
  __syncthreads();

  const float p = (tid < 80) ? h2[tid] * W3[tid] : 0.f;
  const float z = block_sum256(p, red);
  if (tid == 0) {
    out[b] = 1.0f / (1.0f + expf(-(z + b3[0])));
  }
}

// ---------------------------------------------------------------------------
extern "C" void kernel_launch(void* const* d_in, const int* in_sizes, int n_in,
                              void* d_out, int out_size, void* d_ws, size_t ws_size,
                              hipStream_t stream) {
  (void)in_sizes; (void)n_in; (void)out_size; (void)ws_size;
  const int* uid = (const int*)d_in[0];
  const int* u1  = (const int*)d_in[1];
  const int* u2  = (const int*)d_in[2];
  const int* u3  = (const int*)d_in[3];
  const int* u4  = (const int*)d_in[4];
  const int* ig  = (const int*)d_in[5];
  const int* ish = (const int*)d_in[6];
  const int* ici = (const int*)d_in[7];
  const int* sg  = (const int*)d_in[8];
  const int* ss  = (const int*)d_in[9];
  const int* scd = (const int*)d_in[10];
  const int* lg  = (const int*)d_in[11];
  const int* ls  = (const int*)d_in[12];
  const int* lcd = (const int*)d_in[13];
  const float* emb = (const float*)d_in[14];
  const float* Hm  = (const float*)d_in[15];
  const float* sWq = (const float*)d_in[16];
  const float* sbq = (const float*)d_in[17];
  const float* sWk = (const float*)d_in[18];
  const float* sbk = (const float*)d_in[19];
  const float* sWv = (const float*)d_in[20];
  const float* sbv = (const float*)d_in[21];
  const float* sWo = (const float*)d_in[22];
  const float* sbo = (const float*)d_in[23];
  const float* lWq = (const float*)d_in[24];
  const float* lbq = (const float*)d_in[25];
  const float* lWk = (const float*)d_in[26];
  const float* lbk = (const float*)d_in[27];
  const float* lWv = (const float*)d_in[28];
  const float* lbv = (const float*)d_in[29];
  const float* lWo = (const float*)d_in[30];
  const float* lbo = (const float*)d_in[31];
  const float* W1 = (const float*)d_in[32];
  const float* b1 = (const float*)d_in[33];
  const float* g1 = (const float*)d_in[34];
  const float* be1 = (const float*)d_in[35];
  const float* W2 = (const float*)d_in[36];
  const float* b2 = (const float*)d_in[37];
  const float* g2 = (const float*)d_in[38];
  const float* be2 = (const float*)d_in[39];
  const float* W3 = (const float*)d_in[40];
  const float* b3 = (const float*)d_in[41];
  float* out = (float*)d_out;

  // workspace: [gsc 2MB][sel 192KB][osm_s 192KB][osm_l 192KB]
  signed char* gsc = (signed char*)d_ws;
  int* sel = (int*)((char*)d_ws + (size_t)BB * LLx);
  float* osm_s = (float*)(sel + BB * TOPKx);
  float* osm_l = osm_s + BB * 48;

  k_score<<<dim3(LLx / 128, BB), dim3(128), 0, stream>>>(
      lg, ls, lcd, ig, ish, ici, emb, Hm, gsc);
  k_topk<<<dim3(BB), dim3(256), 0, stream>>>(gsc, sel);
  k_mha_short_h<<<dim3(BB, 8), dim3(128), 0, stream>>>(
      sg, ss, scd, ig, ish, ici, emb,
      sWq, sbq, sWk, sbk, sWv, sbv, osm_s);
  k_mha_long_h<<<dim3(BB, 8), dim3(64), 0, stream>>>(
      lg, ls, lcd, ig, ish, ici, emb,
      lWq, lbq, lWk, lbk, lWv, lbv, sel, osm_l);
  k_mlp<<<dim3(BB), dim3(256), 0, stream>>>(
      uid, u1, u2, u3, u4, ig, ish, ici, emb,
      osm_s, osm_l, sWo, sbo, lWo, lbo,
      W1, b1, g1, be1, W2, b2, g2, be2, W3, b3, out);
}

// Round 12
// 304.740 us; speedup vs baseline: 1.2651x; 1.0207x over previous
//
#include <hip/hip_runtime.h>
#include <math.h>

#define BB 1024
#define LSx 128
#define LLx 2048
#define TOPKx 48

// ---------------------------------------------------------------------------
// Kernel 1: long-term LSH scoring (VERBATIM R11 verified; at its gather
// request-rate wall ~83us: 0.74 lines/cyc/CU, 6 structural variants converge).
// ---------------------------------------------------------------------------
__global__ __launch_bounds__(128, 4) void k_score(
    const int* __restrict__ lg, const int* __restrict__ lsh, const int* __restrict__ lc,
    const int* __restrict__ ig, const int* __restrict__ ish, const int* __restrict__ ici,
    const float* __restrict__ emb, const float* __restrict__ Hm,
    signed char* __restrict__ gsc)
{
  __shared__ float Xitem[48];
  __shared__ int icode[16];
  __shared__ __align__(16) float4 xsh[128][5];   // slot 4 = pad -> 20-word stride
  const int b = blockIdx.y, tid = threadIdx.x;

  const int l = blockIdx.x * 128 + tid;
  const size_t off = (size_t)b * LLx + l;
  const int gid = lg[off];

  if (tid < 48) {
    const int seg = tid >> 4, e = tid & 15;
    const int id = (seg == 0) ? ig[b] : (seg == 1) ? ish[b] : ici[b];
    Xitem[tid] = emb[(size_t)id * 16 + e];
  }
  __syncthreads();
  if (tid < 16) {
    float dd = 0.f;
    for (int e = 0; e < 48; ++e) dd += Xitem[e] * Hm[e * 16 + tid];
    icode[tid] = (dd > 0.f) ? 1 : (dd < 0.f ? -1 : 0);
  }

  const int srow = tid >> 2;
  const int q = tid & 3;
  const size_t bbase = (size_t)b * LLx + (size_t)blockIdx.x * 128;

  float d[16];
  #pragma unroll
  for (int m = 0; m < 16; ++m) d[m] = 0.f;

  #pragma unroll
  for (int seg = 0; seg < 3; ++seg) {
    const int* idarr = (seg == 0) ? lg : (seg == 1) ? lsh : lc;
    #pragma unroll
    for (int jj = 0; jj < 4; ++jj) {
      const int pos = jj * 32 + srow;
      const int id = idarr[bbase + pos];
      xsh[pos][q] = *(const float4*)(emb + (size_t)id * 16 + q * 4);
    }
    __syncthreads();
    if (gid != 0) {
      float x[16];
      #pragma unroll
      for (int qq = 0; qq < 4; ++qq) {
        const float4 r = xsh[tid][qq];
        x[qq * 4 + 0] = r.x; x[qq * 4 + 1] = r.y;
        x[qq * 4 + 2] = r.z; x[qq * 4 + 3] = r.w;
      }
      const float* hb = Hm + seg * 256;
      #pragma unroll
      for (int i = 0; i < 16; ++i) {
        const float xi = x[i];
        #pragma unroll
        for (int mc = 0; mc < 4; ++mc) {
          const float4 h4 = *(const float4*)(hb + i * 16 + mc * 4);
          d[mc * 4 + 0] += xi * h4.x;
          d[mc * 4 + 1] += xi * h4.y;
          d[mc * 4 + 2] += xi * h4.z;
          d[mc * 4 + 3] += xi * h4.w;
        }
      }
    }
    if (seg < 2) __syncthreads();
  }

  int sc = -1;
  if (gid != 0) {
    sc = 0;
    #pragma unroll
    for (int m = 0; m < 16; ++m) {
      const int cs = (d[m] > 0.f) ? 1 : (d[m] < 0.f ? -1 : 0);
      sc += (cs == icode[m]) ? 1 : 0;
    }
  }
  gsc[off] = (signed char)sc;
}

// ---------------------------------------------------------------------------
// Kernel 2: top-k selection (VERBATIM R6 verified).
// ---------------------------------------------------------------------------
__global__ __launch_bounds__(256) void k_topk(
    const signed char* __restrict__ gsc, int* __restrict__ sel)
{
  __shared__ int hist[18];
  __shared__ int cnt_above;
  __shared__ int wsum[4];
  const int b = blockIdx.x, tid = threadIdx.x;

  const int2 myv = ((const int2*)(gsc + (size_t)b * LLx))[tid];
  signed char loc[8];
  *(int2*)loc = myv;

  if (tid < 18) hist[tid] = 0;
  if (tid == 0) cnt_above = 0;
  __syncthreads();

  #pragma unroll
  for (int j = 0; j < 8; ++j) atomicAdd(&hist[(int)loc[j] + 1], 1);
  __syncthreads();

  int above = 0, tval = -1, need = 0;
  for (int s = 16; s >= -1; --s) {
    const int c = hist[s + 1];
    if (above + c >= TOPKx) { tval = s; need = TOPKx - above; break; }
    above += c;
  }

  const int base_l = tid * (LLx / 256);
  int cnt = 0;
  #pragma unroll
  for (int j = 0; j < 8; ++j) cnt += ((int)loc[j] == tval) ? 1 : 0;
  int v = cnt;
  const int lane = tid & 63, wave = tid >> 6;
  #pragma unroll
  for (int o = 1; o < 64; o <<= 1) {
    const int u = __shfl_up(v, o, 64);
    if (lane >= o) v += u;
  }
  if (lane == 63) wsum[wave] = v;
  __syncthreads();
  int rank = v - cnt;
  for (int w = 0; w < wave; ++w) rank += wsum[w];

  #pragma unroll
  for (int j = 0; j < 8; ++j) {
    const int l = base_l + j;
    const int s = (int)loc[j];
    if (s > tval) {
      const int slot = atomicAdd(&cnt_above, 1);
      sel[b * TOPKx + slot] = l;
    } else if (s == tval) {
      if (rank < need) sel[b * TOPKx + above + rank] = l;
      ++rank;
    }
  }
}

// ---------------------------------------------------------------------------
// Kernel 3: MERGED per-head MHA. Grid (BB, 16), 128 threads.
//   blockIdx.y < 8 : short head h = y (VERBATIM R10 short path)
//   blockIdx.y >= 8: long head h = y-8 (VERBATIM R10 long path; threads
//                    64..127 are barrier-only — all guards unchanged ->
//                    same nval, bit-identical results)
// Removes one launch boundary; long blocks hide inside short's shadow.
// ---------------------------------------------------------------------------
__global__ __launch_bounds__(128) void k_mha(
    const int* __restrict__ sg, const int* __restrict__ ss, const int* __restrict__ scd,
    const int* __restrict__ lg, const int* __restrict__ ls, const int* __restrict__ lcd,
    const int* __restrict__ ig, const int* __restrict__ ish, const int* __restrict__ ici,
    const float* __restrict__ emb,
    const float* __restrict__ sWq, const float* __restrict__ sbq,
    const float* __restrict__ sWk, const float* __restrict__ sbk,
    const float* __restrict__ sWv, const float* __restrict__ sbv,
    const float* __restrict__ lWq, const float* __restrict__ lbq,
    const float* __restrict__ lWk, const float* __restrict__ lbk,
    const float* __restrict__ lWv, const float* __restrict__ lbv,
    const int* __restrict__ sel,
    float* __restrict__ osm_s, float* __restrict__ osm_l)
{
  __shared__ float Xitem[48];
  __shared__ float qh[6];
  __shared__ float scs[LSx];
  __shared__ float vhT[6][LSx + 4];
  __shared__ unsigned char validf[LSx];
  const int b = blockIdx.x, tid = threadIdx.x;
  const bool is_long = blockIdx.y >= 8;
  const int h = is_long ? (blockIdx.y - 8) : blockIdx.y;

  const float* Wq = is_long ? lWq : sWq;
  const float* bq = is_long ? lbq : sbq;
  const float* Wk = is_long ? lWk : sWk;
  const float* bk = is_long ? lbk : sbk;
  const float* Wv = is_long ? lWv : sWv;
  const float* bv = is_long ? lbv : sbv;
  const int K = is_long ? TOPKx : LSx;

  if (tid < 48) {
    const int seg = tid >> 4, e = tid & 15;
    const int id = (seg == 0) ? ig[b] : (seg == 1) ? ish[b] : ici[b];
    Xitem[tid] = emb[(size_t)id * 16 + e];
  }
  __syncthreads();
  if (tid < 6) {
    const int col = h * 6 + tid;
    float a = bq[col];
    for (int e = 0; e < 48; ++e) a += Xitem[e] * Wq[e * 48 + col];
    qh[tid] = a;
  }

  int gid = 0, sid = 0, cid = 0;
  if (!is_long) {
    const size_t off = (size_t)b * LSx + tid;
    gid = sg[off]; sid = ss[off]; cid = scd[off];
  } else if (tid < TOPKx) {
    const int pos = sel[b * TOPKx + tid];
    const size_t off = (size_t)b * LLx + pos;
    gid = lg[off]; sid = ls[off]; cid = lcd[off];
  }
  const int nval = __syncthreads_count((tid < K) && (gid != 0));  // qh visible

  if (tid < K) {
    // short mask: pos < slen; long mask: gid != 0 (verbatim semantics)
    validf[tid] = is_long ? (unsigned char)(gid != 0) : (unsigned char)(tid < nval);
    float kh[6], vh[6];
    #pragma unroll
    for (int j = 0; j < 6; ++j) { kh[j] = bk[h * 6 + j]; vh[j] = bv[h * 6 + j]; }
    const int ids3[3] = {gid, sid, cid};
    #pragma unroll
    for (int seg = 0; seg < 3; ++seg) {
      const float* row = emb + (size_t)ids3[seg] * 16;
      #pragma unroll
      for (int i4 = 0; i4 < 4; ++i4) {
        const float4 xv = ((const float4*)row)[i4];
        const float xs[4] = {xv.x, xv.y, xv.z, xv.w};
        #pragma unroll
        for (int c = 0; c < 4; ++c) {
          const int e = seg * 16 + i4 * 4 + c;
          const float* wkr = Wk + e * 48 + h * 6;   // uniform -> scalar loads
          const float* wvr = Wv + e * 48 + h * 6;
          const float xe = xs[c];
          #pragma unroll
          for (int j = 0; j < 6; ++j) {
            kh[j] += xe * wkr[j];
            vh[j] += xe * wvr[j];
          }
        }
      }
    }
    float s = 0.f;
    #pragma unroll
    for (int d = 0; d < 6; ++d) s += qh[d] * kh[d];
    scs[tid] = s * 0.40824829046386301637f;         // 1/sqrt(6)
    #pragma unroll
    for (int j = 0; j < 6; ++j) vhT[j][tid] = vh[j];
  }
  __syncthreads();

  // ---- softmax: lanes 0..15 replicate the verified 16-lane group ----
  if (tid < 16) {
    const int l16 = tid;
    float amax = -INFINITY;
    for (int k = l16; k < K; k += 16) if (validf[k]) amax = fmaxf(amax, scs[k]);
    #pragma unroll
    for (int m = 1; m < 16; m <<= 1) amax = fmaxf(amax, __shfl_xor(amax, m, 16));
    if (nval == 0) {
      for (int k = l16; k < K; k += 16) scs[k] = 1.0f / (float)K;
    } else {
      float ssum = 0.f;
      for (int k = l16; k < K; k += 16) {
        const float ev = validf[k] ? expf(scs[k] - amax) : 0.f;
        scs[k] = ev;
        ssum += ev;
      }
      #pragma unroll
      for (int m = 1; m < 16; m <<= 1) ssum += __shfl_xor(ssum, m, 16);
      const float inv = 1.0f / ssum;
      for (int k = l16; k < K; k += 16) scs[k] *= inv;
    }
  }
  __syncthreads();

  // ---- PV: 6 threads, sequential k (verbatim order) ----
  if (tid < 6) {
    float a = 0.f;
    for (int k = 0; k < K; ++k) a += scs[k] * vhT[tid][k];
    float* dst = is_long ? osm_l : osm_s;
    dst[b * 48 + h * 6 + tid] = a;
  }
}

// ---------------------------------------------------------------------------
// Kernel 4: output projections + MLP head (VERBATIM R10 verified).
// ---------------------------------------------------------------------------
__device__ __forceinline__ float block_sum256(float v, float* red) {
  #pragma unroll
  for (int m = 32; m >= 1; m >>= 1) v += __shfl_xor(v, m, 64);
  const int lane = threadIdx.x & 63, wave = threadIdx.x >> 6;
  if (lane == 0) red[wave] = v;
  __syncthreads();
  const float t = red[0] + red[1] + red[2] + red[3];
  __syncthreads();
  return t;
}

__global__ __launch_bounds__(256) void k_mlp(
    const int* __restrict__ uid, const int* __restrict__ u1, const int* __restrict__ u2,
    const int* __restrict__ u3, const int* __restrict__ u4,
    const int* __restrict__ ig, const int* __restrict__ ish, const int* __restrict__ ici,
    const float* __restrict__ emb,
    const float* __restrict__ osm_s, const float* __restrict__ osm_l,
    const float* __restrict__ sWo, const float* __restrict__ sbo,
    const float* __restrict__ lWo, const float* __restrict__ lbo,
    const float* __restrict__ W1, const float* __restrict__ b1,
    const float* __restrict__ g1, const float* __restrict__ be1,
    const float* __restrict__ W2, const float* __restrict__ b2,
    const float* __restrict__ g2, const float* __restrict__ be2,
    const float* __restrict__ W3, const float* __restrict__ b3,
    float* __restrict__ out)
{
  __shared__ __align__(16) float x[224];
  __shared__ __align__(16) float h1[200];
  __shared__ float h2[80];
  __shared__ float red[4];
  __shared__ float osm_sl[48], osm_ll[48];
  const int b = blockIdx.x, tid = threadIdx.x;

  if (tid < 128) {
    const int e = tid & 15;
    int id;
    if (tid < 48) {
      const int seg = tid >> 4;
      id = (seg == 0) ? ig[b] : (seg == 1) ? ish[b] : ici[b];
    } else {
      const int f = (tid - 48) >> 4;
      id = (f == 0) ? uid[b] : (f == 1) ? u1[b] : (f == 2) ? u2[b] : (f == 3) ? u3[b] : u4[b];
    }
    x[tid] = emb[(size_t)id * 16 + e];
  } else if (tid < 176) {
    osm_sl[tid - 128] = osm_s[b * 48 + (tid - 128)];
  } else if (tid < 224) {
    osm_ll[tid - 176] = osm_l[b * 48 + (tid - 176)];
  }
  __syncthreads();

  if (tid < 48) {
    float r = sbo[tid];
    for (int j = 0; j < 48; ++j) r += osm_sl[j] * sWo[j * 48 + tid];
    x[128 + tid] = r;
  } else if (tid >= 64 && tid < 112) {
    const int c = tid - 64;
    float r = lbo[c];
    for (int j = 0; j < 48; ++j) r += osm_ll[j] * lWo[j * 48 + c];
    x[176 + c] = r;
  }
  __syncthreads();

  float v = 0.f;
  if (tid < 200) {
    v = b1[tid];
    for (int i4 = 0; i4 < 56; ++i4) {
      const float4 xv = *(const float4*)(x + i4 * 4);
      const float* w = W1 + i4 * 4 * 200 + tid;
      v += xv.x * w[0];
      v += xv.y * w[200];
      v += xv.z * w[400];
      v += xv.w * w[600];
    }
  }
  const float mean1 = block_sum256((tid < 200) ? v : 0.f, red) * (1.0f / 200.0f);
  const float dv = (tid < 200) ? (v - mean1) : 0.f;
  const float var1 = block_sum256(dv * dv, red) * (1.0f / 200.0f);
  if (tid < 200) {
    const float y = (v - mean1) * rsqrtf(var1 + 1e-3f) * g1[tid] + be1[tid];
    h1[tid] = fmaxf(y, 0.f);
  }
  __syncthreads();

  float v2 = 0.f;
  if (tid < 80) {
    v2 = b2[tid];
    for (int i4 = 0; i4 < 50; ++i4) {
      const float4 xv = *(const float4*)(h1 + i4 * 4);
      const float* w = W2 + i4 * 4 * 80 + tid;
      v2 += xv.x * w[0];
      v2 += xv.y * w[80];
      v2 += xv.z * w[160];
      v2 += xv.w * w[240];
    }
  }
  const float mean2 = block_sum256((tid < 80) ? v2 : 0.f, red) * (1.0f / 80.0f);
  const float dv2 = (tid < 80) ? (v2 - mean2) : 0.f;
  const float var2 = block_sum256(dv2 * dv2, red) * (1.0f / 80.0f);
  if (tid < 80) {
    const float y = (v2 - mean2) * rsqrtf(var2 + 1e-3f) * g2[tid] + be2[tid];
    h2[tid] = fmaxf(y, 0.f);
  }
  __syncthreads();

  const float p = (tid < 80) ? h2[tid] * W3[tid] : 0.f;
  const float z = block_sum256(p, red);
  if (tid == 0) {
    out[b] = 1.0f / (1.0f + expf(-(z + b3[0])));
  }
}

// ---------------------------------------------------------------------------
extern "C" void kernel_launch(void* const* d_in, const int* in_sizes, int n_in,
                              void* d_out, int out_size, void* d_ws, size_t ws_size,
                              hipStream_t stream) {
  (void)in_sizes; (void)n_in; (void)out_size; (void)ws_size;
  const int* uid = (const int*)d_in[0];
  const int* u1  = (const int*)d_in[1];
  const int* u2  = (const int*)d_in[2];
  const int* u3  = (const int*)d_in[3];
  const int* u4  = (const int*)d_in[4];
  const int* ig  = (const int*)d_in[5];
  const int* ish = (const int*)d_in[6];
  const int* ici = (const int*)d_in[7];
  const int* sg  = (const int*)d_in[8];
  const int* ss  = (const int*)d_in[9];
  const int* scd = (const int*)d_in[10];
  const int* lg  = (const int*)d_in[11];
  const int* ls  = (const int*)d_in[12];
  const int* lcd = (const int*)d_in[13];
  const float* emb = (const float*)d_in[14];
  const float* Hm  = (const float*)d_in[15];
  const float* sWq = (const float*)d_in[16];
  const float* sbq = (const float*)d_in[17];
  const float* sWk = (const float*)d_in[18];
  const float* sbk = (const float*)d_in[19];
  const float* sWv = (const float*)d_in[20];
  const float* sbv = (const float*)d_in[21];
  const float* sWo = (const float*)d_in[22];
  const float* sbo = (const float*)d_in[23];
  const float* lWq = (const float*)d_in[24];
  const float* lbq = (const float*)d_in[25];
  const float* lWk = (const float*)d_in[26];
  const float* lbk = (const float*)d_in[27];
  const float* lWv = (const float*)d_in[28];
  const float* lbv = (const float*)d_in[29];
  const float* lWo = (const float*)d_in[30];
  const float* lbo = (const float*)d_in[31];
  const float* W1 = (const float*)d_in[32];
  const float* b1 = (const float*)d_in[33];
  const float* g1 = (const float*)d_in[34];
  const float* be1 = (const float*)d_in[35];
  const float* W2 = (const float*)d_in[36];
  const float* b2 = (const float*)d_in[37];
  const float* g2 = (const float*)d_in[38];
  const float* be2 = (const float*)d_in[39];
  const float* W3 = (const float*)d_in[40];
  const float* b3 = (const float*)d_in[41];
  float* out = (float*)d_out;

  // workspace: [gsc 2MB][sel 192KB][osm_s 192KB][osm_l 192KB]
  signed char* gsc = (signed char*)d_ws;
  int* sel = (int*)((char*)d_ws + (size_t)BB * LLx);
  float* osm_s = (float*)(sel + BB * TOPKx);
  float* osm_l = osm_s + BB * 48;

  k_score<<<dim3(LLx / 128, BB), dim3(128), 0, stream>>>(
      lg, ls, lcd, ig, ish, ici, emb, Hm, gsc);
  k_topk<<<dim3(BB), dim3(256), 0, stream>>>(gsc, sel);
  k_mha<<<dim3(BB, 16), dim3(128), 0, stream>>>(
      sg, ss, scd, lg, ls, lcd, ig, ish, ici, emb,
      sWq, sbq, sWk, sbk, sWv, sbv,
      lWq, lbq, lWk, lbk, lWv, lbv, sel, osm_s, osm_l);
  k_mlp<<<dim3(BB), dim3(256), 0, stream>>>(
      uid, u1, u2, u3, u4, ig, ish, ici, emb,
      osm_s, osm_l, sWo, sbo, lWo, lbo,
      W1, b1, g1, be1, W2, b2, g2, be2, W3, b3, out);
}